// Round 1
// baseline (453.325 us; speedup 1.0000x reference)
//
#include <hip/hip_runtime.h>
#include <cmath>
#include <climits>

#define EMBED 64
#define KTOP 11        // top_n + 1 (self match included, dropped at output)
#define NB   1024
#define BLOCK 256
#define NWAVE (BLOCK / 64)

// Insert (v,i) into per-thread sorted top-KTOP list (desc value, asc index).
// Fast path: one compare against current min.
__device__ __forceinline__ void topk_insert(float (&vals)[KTOP], int (&idxs)[KTOP],
                                            float v, int i) {
  float last = vals[KTOP - 1];
  if (v < last) return;
  if (v == last && i >= idxs[KTOP - 1]) return;
  float cv = v; int ci = i;
#pragma unroll
  for (int j = 0; j < KTOP; ++j) {
    bool better = (cv > vals[j]) || (cv == vals[j] && ci < idxs[j]);
    if (better) {
      float tv = vals[j]; int ti = idxs[j];
      vals[j] = cv; idxs[j] = ci;
      cv = tv; ci = ti;
    }
  }
}

// Merge 64 lanes' sorted top-KTOP lists into wave top-KTOP, written to LDS
// (wv/wi point at this wave's KTOP-slot). Butterfly argmax per round; winner
// lane pops its head. (val,idx) pairs are unique -> deterministic winner.
__device__ __forceinline__ void wave_merge(float (&vals)[KTOP], int (&idxs)[KTOP],
                                           float* wv, int* wi, int lane) {
#pragma unroll
  for (int round = 0; round < KTOP; ++round) {
    float v = vals[0]; int i = idxs[0]; int l = lane;
#pragma unroll
    for (int off = 32; off > 0; off >>= 1) {
      float ov = __shfl_xor(v, off, 64);
      int   oi = __shfl_xor(i, off, 64);
      int   ol = __shfl_xor(l, off, 64);
      if (ov > v || (ov == v && oi < i)) { v = ov; i = oi; l = ol; }
    }
    if (l == lane) {  // I won: pop my head
#pragma unroll
      for (int j = 0; j < KTOP - 1; ++j) { vals[j] = vals[j + 1]; idxs[j] = idxs[j + 1]; }
      vals[KTOP - 1] = -INFINITY; idxs[KTOP - 1] = INT_MAX;
    }
    if (lane == 0) { wv[round] = v; wi[round] = i; }
  }
}

__global__ __launch_bounds__(BLOCK) void sim_pass1(
    const float* __restrict__ emb, const int* __restrict__ user_id,
    float* __restrict__ cand_val, int* __restrict__ cand_idx, int V) {
  __shared__ float t[EMBED];
  __shared__ float wv[NWAVE * KTOP];
  __shared__ int   wi[NWAVE * KTOP];

  const int lane = threadIdx.x & 63;
  const int wid  = threadIdx.x >> 6;

  const int uid = *user_id;
  if (threadIdx.x < EMBED) t[threadIdx.x] = emb[(size_t)uid * EMBED + threadIdx.x];
  __syncthreads();

  float4 tv[EMBED / 4];
#pragma unroll
  for (int j = 0; j < EMBED / 4; ++j) tv[j] = ((const float4*)t)[j];

  float vals[KTOP]; int idxs[KTOP];
#pragma unroll
  for (int j = 0; j < KTOP; ++j) { vals[j] = -INFINITY; idxs[j] = INT_MAX; }

  const int stride = gridDim.x * BLOCK;
  for (int r = blockIdx.x * BLOCK + threadIdx.x; r < V; r += stride) {
    const float4* rp = (const float4*)(emb + (size_t)r * EMBED);
    float dot = 0.f, nr = 0.f;
#pragma unroll
    for (int j = 0; j < EMBED / 4; ++j) {
      float4 v = rp[j];
      dot = fmaf(v.x, tv[j].x, dot); dot = fmaf(v.y, tv[j].y, dot);
      dot = fmaf(v.z, tv[j].z, dot); dot = fmaf(v.w, tv[j].w, dot);
      nr  = fmaf(v.x, v.x, nr);      nr  = fmaf(v.y, v.y, nr);
      nr  = fmaf(v.z, v.z, nr);      nr  = fmaf(v.w, v.w, nr);
    }
    // scaled sim: dot / ||row||  (division by ||target|| deferred — positive
    // common factor, does not affect ordering)
    float sim = dot / sqrtf(nr);
    topk_insert(vals, idxs, sim, r);
  }

  wave_merge(vals, idxs, &wv[wid * KTOP], &wi[wid * KTOP], lane);
  __syncthreads();

  if (wid == 0) {  // wave 0 merges NWAVE*KTOP entries -> block top-KTOP
    float v = (lane < NWAVE * KTOP) ? wv[lane] : -INFINITY;
    int   i = (lane < NWAVE * KTOP) ? wi[lane] : INT_MAX;
#pragma unroll
    for (int round = 0; round < KTOP; ++round) {
      float bv = v; int bi = i; int bl = lane;
#pragma unroll
      for (int off = 32; off > 0; off >>= 1) {
        float ov = __shfl_xor(bv, off, 64);
        int   oi = __shfl_xor(bi, off, 64);
        int   ol = __shfl_xor(bl, off, 64);
        if (ov > bv || (ov == bv && oi < bi)) { bv = ov; bi = oi; bl = ol; }
      }
      if (bl == lane) { v = -INFINITY; i = INT_MAX; }
      if (lane == 0) {
        cand_val[blockIdx.x * KTOP + round] = bv;
        cand_idx[blockIdx.x * KTOP + round] = bi;
      }
    }
  }
}

__global__ __launch_bounds__(BLOCK) void sim_pass2(
    const float* __restrict__ emb, const int* __restrict__ user_id,
    const float* __restrict__ cand_val, const int* __restrict__ cand_idx,
    float* __restrict__ out, int topn, int ncand) {
  __shared__ float wv[NWAVE * KTOP];
  __shared__ int   wi[NWAVE * KTOP];
  __shared__ float s_nt;

  const int lane = threadIdx.x & 63;
  const int wid  = threadIdx.x >> 6;

  if (wid == 0) {  // compute ||target|| on wave 0
    const int uid = *user_id;
    float x = (lane < EMBED) ? emb[(size_t)uid * EMBED + lane] : 0.f;
    float s = x * x;
#pragma unroll
    for (int off = 32; off > 0; off >>= 1) s += __shfl_xor(s, off, 64);
    if (lane == 0) s_nt = sqrtf(s);
  }

  float vals[KTOP]; int idxs[KTOP];
#pragma unroll
  for (int j = 0; j < KTOP; ++j) { vals[j] = -INFINITY; idxs[j] = INT_MAX; }

  for (int c = threadIdx.x; c < ncand; c += BLOCK)
    topk_insert(vals, idxs, cand_val[c], cand_idx[c]);

  wave_merge(vals, idxs, &wv[wid * KTOP], &wi[wid * KTOP], lane);
  __syncthreads();

  if (wid == 0) {
    float v = (lane < NWAVE * KTOP) ? wv[lane] : -INFINITY;
    int   i = (lane < NWAVE * KTOP) ? wi[lane] : INT_MAX;
    const float nt = s_nt;
#pragma unroll
    for (int round = 0; round < KTOP; ++round) {
      float bv = v; int bi = i; int bl = lane;
#pragma unroll
      for (int off = 32; off > 0; off >>= 1) {
        float ov = __shfl_xor(bv, off, 64);
        int   oi = __shfl_xor(bi, off, 64);
        int   ol = __shfl_xor(bl, off, 64);
        if (ov > bv || (ov == bv && oi < bi)) { bv = ov; bi = oi; bl = ol; }
      }
      if (bl == lane) { v = -INFINITY; i = INT_MAX; }
      // round 0 is the self match -> dropped (matches ref's top_vals[1:])
      if (lane == 0 && round >= 1 && round <= topn) {
        out[round - 1]        = bv / nt;       // similarity value
        out[topn + round - 1] = (float)bi;     // index, as float
      }
    }
  }
}

extern "C" void kernel_launch(void* const* d_in, const int* in_sizes, int n_in,
                              void* d_out, int out_size, void* d_ws, size_t ws_size,
                              hipStream_t stream) {
  const float* emb = (const float*)d_in[0];
  const int*   uid = (const int*)d_in[1];
  // d_in[2] = top_n, but it is derivable host-side: out_size = 2 * top_n
  const int V    = in_sizes[0] / EMBED;
  const int topn = out_size / 2;  // 10 -> KTOP = 11 list covers it

  float* cand_val = (float*)d_ws;
  int*   cand_idx = (int*)((char*)d_ws + (size_t)NB * KTOP * sizeof(float));

  sim_pass1<<<NB, BLOCK, 0, stream>>>(emb, uid, cand_val, cand_idx, V);
  sim_pass2<<<1, BLOCK, 0, stream>>>(emb, uid, cand_val, cand_idx,
                                     (float*)d_out, topn, NB * KTOP);
}